// Round 1
// baseline (259.888 us; speedup 1.0000x reference)
//
#include <hip/hip_runtime.h>
#include <math.h>

#define BATCH 256
#define QL 50
#define EMB 50
#define DL 2000
#define NB 11
#define SEG 4        // d-dimension split per batch -> 1024 blocks
#define RPS 500      // rows per segment (DL/SEG)
#define TPB 256
#define RPT 2        // d rows per thread (RPT*TPB=512 >= RPS)

// ---------------- main kernel: cosine sim + histogram ----------------
__global__ __launch_bounds__(TPB, 2)
void sim_hist_kernel(const float* __restrict__ qe,   // [B,QL,EMB]
                     const float* __restrict__ de,   // [B,DL,EMB]
                     const int*   __restrict__ qid,  // [B,QL]
                     const int*   __restrict__ did,  // [B,DL]
                     unsigned*    __restrict__ g_hist) // [B,QL,NB]
{
    const int bid  = blockIdx.x;
    const int b    = bid >> 2;
    const int seg  = bid & 3;
    const int t    = threadIdx.x;
    const int lane = t & 63;

    __shared__ unsigned s_hist[QL * NB];
    __shared__ float    s_qrn[QL];
    __shared__ int      s_qv[QL];

    const float* qbase = qe + (size_t)b * QL * EMB;

    for (int i = t; i < QL * NB; i += TPB) s_hist[i] = 0u;
    if (t < QL) {
        const float* qr = qbase + t * EMB;
        float ss = 0.f;
        #pragma unroll
        for (int e = 0; e < EMB; ++e) ss = fmaf(qr[e], qr[e], ss);
        s_qrn[t] = 1.0f / (sqrtf(ss) + 1e-8f);
        s_qv[t]  = (qid[(size_t)b * QL + t] > 0) ? 1 : 0;
    }

    // ---- load this thread's d rows into registers, compute inv-norms ----
    float dreg[RPT][EMB];
    float drn[RPT];
    int   dval[RPT];
    const int rowbase = seg * RPS;
    #pragma unroll
    for (int r = 0; r < RPT; ++r) {
        const int  local = r * TPB + t;
        const bool ok    = local < RPS;
        const int  row   = rowbase + (ok ? local : 0);
        const float* src = de + ((size_t)b * DL + row) * EMB;
        float ss = 0.f;
        #pragma unroll
        for (int e = 0; e < EMB; e += 2) {
            const float2 v = *(const float2*)(src + e);
            dreg[r][e]     = v.x;
            dreg[r][e + 1] = v.y;
            ss = fmaf(v.x, v.x, ss);
            ss = fmaf(v.y, v.y, ss);
        }
        drn[r]  = 1.0f / (sqrtf(ss) + 1e-8f);
        dval[r] = (ok && did[(size_t)b * DL + row] > 0) ? 1 : 0;
    }
    __syncthreads();

    // ---- loop over query terms (wave-uniform) ----
    for (int q = 0; q < QL; ++q) {
        if (!s_qv[q]) continue;                 // invalid q term -> zero counts
        const float* qrow = qbase + q * EMB;    // uniform address -> s_load
        const float  qrn  = s_qrn[q];

        float acc0 = 0.f, acc1 = 0.f;
        #pragma unroll
        for (int e = 0; e < EMB; ++e) {
            const float qv = qrow[e];
            acc0 = fmaf(dreg[0][e], qv, acc0);
            acc1 = fmaf(dreg[1][e], qv, acc1);
        }

        int bin0, bin1;
        {
            const float s  = acc0 * qrn * drn[0];
            const float tt = ((s + 1.000001f) * 0.5f) * 10.0f;  // match ref order
            int bb = (int)tt;                    // trunc toward zero, like np int32 cast
            bb = bb < 0 ? 0 : (bb > 10 ? 10 : bb);
            bin0 = dval[0] ? bb : -1;
        }
        {
            const float s  = acc1 * qrn * drn[1];
            const float tt = ((s + 1.000001f) * 0.5f) * 10.0f;
            int bb = (int)tt;
            bb = bb < 0 ? 0 : (bb > 10 ? 10 : bb);
            bin1 = dval[1] ? bb : -1;
        }

        // ballot-based per-wave histogram (avoids hot-bin LDS atomic serialization)
        unsigned cnt = 0;
        #pragma unroll
        for (int bb = 0; bb < NB; ++bb) {
            const unsigned long long m0 = __ballot(bin0 == bb);
            const unsigned long long m1 = __ballot(bin1 == bb);
            if (lane == bb) cnt = (unsigned)(__popcll(m0) + __popcll(m1));
        }
        if (lane < NB && cnt) atomicAdd(&s_hist[q * NB + lane], cnt);
    }

    __syncthreads();
    for (int i = t; i < QL * NB; i += TPB) {
        const unsigned c = s_hist[i];
        if (c) atomicAdd(&g_hist[(size_t)b * QL * NB + i], c);
    }
}

// ---------------- epilogue 1: ffn dot + gate dot per batch ----------------
__global__ __launch_bounds__(TPB)
void ffn_gate_kernel(const unsigned* __restrict__ g_hist,
                     const float* __restrict__ W1,
                     const float* __restrict__ bias,
                     const float* __restrict__ qe,
                     const float* __restrict__ Wg,
                     float* __restrict__ ffn,
                     float* __restrict__ gate)
{
    const int b = blockIdx.x;
    const int t = threadIdx.x;

    float a1 = 0.f;
    for (int i = t; i < QL * NB; i += TPB)
        a1 = fmaf(logf((float)g_hist[(size_t)b * QL * NB + i] + 1e-5f), W1[i], a1);

    float a2 = 0.f;
    for (int i = t; i < QL * EMB; i += TPB)
        a2 = fmaf(qe[(size_t)b * QL * EMB + i], Wg[i], a2);

    #pragma unroll
    for (int off = 32; off > 0; off >>= 1) {
        a1 += __shfl_down(a1, off, 64);
        a2 += __shfl_down(a2, off, 64);
    }
    __shared__ float r1s[4], r2s[4];
    if ((t & 63) == 0) { r1s[t >> 6] = a1; r2s[t >> 6] = a2; }
    __syncthreads();
    if (t == 0) {
        ffn[b]  = r1s[0] + r1s[1] + r1s[2] + r1s[3] + bias[0];
        gate[b] = r2s[0] + r2s[1] + r2s[2] + r2s[3];
    }
}

// ---------------- epilogue 2: softmax over batch + final score ----------------
__global__ __launch_bounds__(TPB)
void score_kernel(const float* __restrict__ ffn,
                  const float* __restrict__ gate,
                  float* __restrict__ out)
{
    const int t = threadIdx.x;  // one block of 256 == BATCH
    __shared__ float buf[4];
    __shared__ float sM, sZ, sS;

    const float g = gate[t];

    float m = g;
    #pragma unroll
    for (int off = 32; off > 0; off >>= 1) m = fmaxf(m, __shfl_down(m, off, 64));
    if ((t & 63) == 0) buf[t >> 6] = m;
    __syncthreads();
    if (t == 0) sM = fmaxf(fmaxf(buf[0], buf[1]), fmaxf(buf[2], buf[3]));
    __syncthreads();

    const float e = expf(g - sM);
    float z = e;
    #pragma unroll
    for (int off = 32; off > 0; off >>= 1) z += __shfl_down(z, off, 64);
    __syncthreads();
    if ((t & 63) == 0) buf[t >> 6] = z;
    __syncthreads();
    if (t == 0) sZ = buf[0] + buf[1] + buf[2] + buf[3];
    __syncthreads();

    float p = e / sZ;           // out_tgn[t]
    float s = p;
    #pragma unroll
    for (int off = 32; off > 0; off >>= 1) s += __shfl_down(s, off, 64);
    __syncthreads();
    if ((t & 63) == 0) buf[t >> 6] = s;
    __syncthreads();
    if (t == 0) sS = buf[0] + buf[1] + buf[2] + buf[3];   // == sum(softmax) ~ 1
    __syncthreads();

    out[t] = ffn[t] * sS;
}

// ---------------- launcher ----------------
extern "C" void kernel_launch(void* const* d_in, const int* in_sizes, int n_in,
                              void* d_out, int out_size, void* d_ws, size_t ws_size,
                              hipStream_t stream)
{
    const float* qe  = (const float*)d_in[0];
    const float* de  = (const float*)d_in[1];
    const float* W1  = (const float*)d_in[2];
    const float* b1  = (const float*)d_in[3];
    const float* Wg  = (const float*)d_in[4];
    const int*   qid = (const int*)d_in[5];
    const int*   did = (const int*)d_in[6];
    float* out = (float*)d_out;

    unsigned* g_hist = (unsigned*)d_ws;
    const size_t hist_bytes = (size_t)BATCH * QL * NB * sizeof(unsigned); // 563,200 B
    float* ffn  = (float*)((char*)d_ws + hist_bytes);
    float* gate = ffn + BATCH;

    hipMemsetAsync(g_hist, 0, hist_bytes, stream);
    sim_hist_kernel<<<BATCH * SEG, TPB, 0, stream>>>(qe, de, qid, did, g_hist);
    ffn_gate_kernel<<<BATCH, TPB, 0, stream>>>(g_hist, W1, b1, qe, Wg, ffn, gate);
    score_kernel<<<1, TPB, 0, stream>>>(ffn, gate, out);
}